// Round 12
// baseline (442.582 us; speedup 1.0000x reference)
//
#include <hip/hip_runtime.h>
#include <hip/hip_fp16.h>

// Fixed problem shape
#define TOK   64
#define INF   4096
#define OUTF  11008
#define NUMEL (OUTF * INF)        // 45088768
#define NSLC  (NUMEL / 64)        // 704512 64-element slices
#define NBLK  (OUTF / 16)         // 688 N-tiles
#define KSPL  16                  // K-split -> 11008 blocks, K=256 each
#define OUTN  (TOK * OUTF)        // 704512 output elems

// Harness dtypes: fp16 arrays arrive as fp32; ints as int32; output fp32.
typedef __attribute__((ext_vector_type(8))) _Float16 half8;
typedef __attribute__((ext_vector_type(4))) _Float16 half4;
typedef __attribute__((ext_vector_type(4))) float floatx4;
typedef __attribute__((ext_vector_type(4), aligned(4))) int int4u;   // dword-aligned dwordx4
typedef __attribute__((ext_vector_type(4))) int int4a;               // 16B-aligned dwordx4

// ---------------------------------------------------------------------------
// Precompute (R8-verified): (a) x fp32 -> fp16 (512 KB, L2-resident GEMM A),
// (b) per-64-slice meta[s] = {c0, outlier mask lo, mask hi, pad} (16 B).
// ---------------------------------------------------------------------------
__global__ __launch_bounds__(256) void precompute_kernel(
    const float* __restrict__ x, const int* __restrict__ fppos, int nf,
    _Float16* __restrict__ x16, int* __restrict__ meta) {
  const int t = blockIdx.x * 256 + threadIdx.x;
  if (t < (TOK * INF) / 4) {
    const floatx4 f = *(const floatx4*)&x[t * 4];
    half4 h;
    h[0] = (_Float16)f[0]; h[1] = (_Float16)f[1];
    h[2] = (_Float16)f[2]; h[3] = (_Float16)f[3];
    *(half4*)&x16[t * 4] = h;
  }
  if (t < NSLC) {
    const int target = t << 6;
    int lo = 0, hi = nf;
    while (lo < hi) {
      const int mid = (lo + hi) >> 1;
      if (fppos[mid] < target) lo = mid + 1; else hi = mid;
    }
    unsigned long long mask = 0ull;
    int j = lo;
    while (j < nf) {                 // mean 0.17 iters; P(>2) ~ 1e-4
      const int d = fppos[j] - target;
      if (d >= 64) break;
      mask |= 1ull << d;
      ++j;
    }
    int4a mv;
    mv[0] = lo;
    mv[1] = (int)(unsigned)(mask & 0xffffffffu);
    mv[2] = (int)(unsigned)(mask >> 32);
    mv[3] = 0;
    *(int4a*)&meta[t * 4] = mv;
  }
}

// ---------------------------------------------------------------------------
// meta_window1 (R3-R11 verified verbatim): compacted i8 index i0 of position
// p0 + 8-bit outlier window. off multiple of 8 -> never straddles halves.
// ---------------------------------------------------------------------------
__device__ __forceinline__ void meta_window1(const int p0, const int4a mv,
                                             int& i0, unsigned& m8) {
  const unsigned mlo = (unsigned)mv[1];
  const unsigned mhi = (unsigned)mv[2];
  const int off = p0 & 63;
  m8 = 0xffu & (off < 32 ? (mlo >> off) : (mhi >> (off - 32)));
  const unsigned bl = (off >= 32) ? mlo : (mlo & ((1u << off) - 1u));
  const unsigned bh = (off >= 32) ? (mhi & ((1u << (off - 32)) - 1u)) : 0u;
  i0 = p0 - mv[0] - (__popc(bl) + __popc(bh));
}

// ---------------------------------------------------------------------------
// finish_slot (R2-R11 verbatim): SLOW path only (>2 outliers in one 8-slot,
// ~1e-6 of slots; wave-uniformly skipped otherwise -> execz branch).
// ---------------------------------------------------------------------------
__device__ __forceinline__ half8 finish_slot(
    const unsigned m8, const int i0, const int p0, const float s,
    const int (&l)[8], const int* __restrict__ i8,
    const float* __restrict__ fpdat, const int n8) {
  const int f = (int)m8;
  float ov[8];
#pragma unroll
  for (int e = 0; e < 8; ++e) ov[e] = 0.f;
  if (f) {
    int fi = p0 - i0;  // c0 + (#outliers below p0)
#pragma unroll
    for (int e = 0; e < 8; ++e) {
      if ((f >> e) & 1) { ov[e] = fpdat[fi]; ++fi; }
    }
  }

  half8 oh;
  if (i0 + 8 <= n8) {
    if (f == 0) {
#pragma unroll
      for (int e = 0; e < 8; ++e) oh[e] = (_Float16)((float)l[e] * s);
    } else {
      int q = 0;
#pragma unroll
      for (int e = 0; e < 8; ++e) {
        const int flg = (f >> e) & 1;
        int lv = l[0];
#pragma unroll
        for (int qq = 1; qq < 8; ++qq) lv = (q == qq) ? l[qq] : lv;
        oh[e] = flg ? (_Float16)ov[e] : (_Float16)((float)lv * s);
        q += 1 - flg;
      }
    }
  } else {
    int c = 0;
    const int m = n8 - 1;
#pragma unroll
    for (int e = 0; e < 8; ++e) {
      const int flg = (f >> e) & 1;
      int idx = i0 + e - c;
      idx = idx < 0 ? 0 : (idx > m ? m : idx);
      oh[e] = flg ? (_Float16)ov[e] : (_Float16)((float)i8[idx] * s);
      c += flg;
    }
  }
  return oh;
}

// ---------------------------------------------------------------------------
// Fused GEMM v13 — max-TLP single-burst waves.
// R1-R11 ledger: every pipelined variant pins at ~90-120 us with NOTHING
// saturated (HBM 20%, VALU 20%, MFMA 2%, occ 40%) -> the limiter is wave
// concurrency/phase sync, not chain depth: 16 launch-synced waves/CU wait
// together then compute together. v13: KSPL=16 -> 11008 blocks; each wave
// owns ONE 64-K chunk (no loop, no banks, ~90 VGPR) -> 5-6 waves/SIMD
// resident, 44032 short waves whose burst/wait/compute phases stagger
// naturally, keeping HBM fed during other waves' compute. Per wave:
// [meta, A(8,L2)] -> wait meta (A rides) -> windows -> [i8 x2, fpdat x4
// unconditional clamped] -> drain once -> dequant + 8 MFMA -> epilogue.
// mfma_f32_16x16x32_f16 mapping + dequant numerics verified R1-R11.
// ---------------------------------------------------------------------------
__global__ __launch_bounds__(256, 4) void gemm_fused(
    const _Float16* __restrict__ x16, const int* __restrict__ i8,
    const float* __restrict__ fpdat, const float* __restrict__ scales,
    const int* __restrict__ meta, float* __restrict__ part,
    const int n8, const int nf) {
  __shared__ float red[4 * 64 * 16];  // 16 KB, epilogue only

  const int tid  = threadIdx.x;
  const int wave = tid >> 6;
  const int lane = tid & 63;
  const int quad = lane >> 4;
  const int ln   = lane & 15;
  const int nt   = blockIdx.x >> 4;
  const int kq   = blockIdx.x & 15;
  const int n0   = nt << 4;
  const int kbas = kq * 256 + wave * 64;    // this wave's single 64-K chunk
  const int qoff = quad * 8;

  const int prow  = n0 + ln;
  const int pbase = prow * INF + kbas;          // lane's positioned chunk base
  const float s   = scales[prow * 4 + (kbas >> 10)];  // chunk in one q-block

  // ---- Burst 1: meta + A fragments (A from L2-resident x16) ----
  const int4a mz = *(const int4a*)&meta[(pbase >> 6) * 4];
  const _Float16* ap = &x16[ln * INF + kbas + qoff];
  const half8 A0 = *(const half8*)&ap[0];
  const half8 A1 = *(const half8*)&ap[16 * INF];
  const half8 A2 = *(const half8*)&ap[32 * INF];
  const half8 A3 = *(const half8*)&ap[48 * INF];
  const half8 A4 = *(const half8*)&ap[32];
  const half8 A5 = *(const half8*)&ap[16 * INF + 32];
  const half8 A6 = *(const half8*)&ap[32 * INF + 32];
  const half8 A7 = *(const half8*)&ap[48 * INF + 32];

  // ---- Windows (waits meta only — A still in flight behind it) ----
  const int p0a = pbase + qoff;
  int i0a, i0b;
  unsigned m8a, m8b;
  meta_window1(p0a, mz, i0a, m8a);
  meta_window1(p0a + 32, mz, i0b, m8b);

  // ---- Burst 2: i8 + unconditional clamped fpdat (static load count) ----
  int la[8], lb[8];
  if (i0a + 8 <= n8) {
    *(int4u*)&la[0] = *(const int4u*)&i8[i0a];
    *(int4u*)&la[4] = *(const int4u*)&i8[i0a + 4];
  }
  if (i0b + 8 <= n8) {
    *(int4u*)&lb[0] = *(const int4u*)&i8[i0b];
    *(int4u*)&lb[4] = *(const int4u*)&i8[i0b + 4];
  }
  float va0, va1, vb0, vb1;
  {
    int fia = p0a - i0a;
    fia = fia < nf - 1 ? fia : nf - 1;
    va0 = fpdat[fia];
    va1 = fpdat[fia + 1 < nf ? fia + 1 : nf - 1];
    int fib = p0a + 32 - i0b;
    fib = fib < nf - 1 ? fib : nf - 1;
    vb0 = fpdat[fib];
    vb1 = fpdat[fib + 1 < nf ? fib + 1 : nf - 1];
  }

// Fast register-only combine (R8/R11-verified): <=2 outliers per slot use
// prefetched V0/V1 by rank; int values via the q-walk select chain.
#define FSLOT(OH, LARR, M8, I0, V0, V1)                                      \
  do {                                                                       \
    const int f_ = (int)(M8);                                                \
    if ((I0) + 8 <= n8) {                                                    \
      if (f_ == 0) {                                                         \
        _Pragma("unroll")                                                    \
        for (int e = 0; e < 8; ++e) OH[e] = (_Float16)((float)LARR[e] * s);  \
      } else {                                                               \
        int q_ = 0;                                                          \
        _Pragma("unroll")                                                    \
        for (int e = 0; e < 8; ++e) {                                        \
          const int flg = (f_ >> e) & 1;                                     \
          const int rank = __popc(f_ & ((1 << e) - 1));                      \
          const float fv = (rank == 0) ? (V0) : (V1);                        \
          int lv = LARR[0];                                                  \
          _Pragma("unroll")                                                  \
          for (int qq = 1; qq < 8; ++qq) lv = (q_ == qq) ? LARR[qq] : lv;    \
          OH[e] = flg ? (_Float16)fv : (_Float16)((float)lv * s);            \
          q_ += 1 - flg;                                                     \
        }                                                                    \
      }                                                                      \
    } else {                                                                 \
      int c_ = 0;                                                            \
      const int m_ = n8 - 1;                                                 \
      _Pragma("unroll")                                                      \
      for (int e = 0; e < 8; ++e) {                                          \
        const int flg = (f_ >> e) & 1;                                       \
        const int rank = __popc(f_ & ((1 << e) - 1));                        \
        const float fv = (rank == 0) ? (V0) : (V1);                          \
        int idx = (I0) + e - c_;                                             \
        idx = idx < 0 ? 0 : (idx > m_ ? m_ : idx);                           \
        OH[e] = flg ? (_Float16)fv : (_Float16)((float)i8[idx] * s);         \
        c_ += flg;                                                           \
      }                                                                      \
    }                                                                        \
  } while (0)

  // ---- Dequant + MFMA ----
  half8 b0, b1;
  FSLOT(b0, la, m8a, i0a, va0, va1);
  FSLOT(b1, lb, m8b, i0b, vb0, vb1);
  if (__any(__popc((int)m8a) > 2 || __popc((int)m8b) > 2)) {
    if (__popc((int)m8a) > 2)
      b0 = finish_slot(m8a, i0a, p0a, s, la, i8, fpdat, n8);
    if (__popc((int)m8b) > 2)
      b1 = finish_slot(m8b, i0b, p0a + 32, s, lb, i8, fpdat, n8);
  }
#undef FSLOT

  floatx4 acc0 = {0,0,0,0}, acc1 = {0,0,0,0}, acc2 = {0,0,0,0}, acc3 = {0,0,0,0};
  acc0 = __builtin_amdgcn_mfma_f32_16x16x32_f16(A0, b0, acc0, 0, 0, 0);
  acc1 = __builtin_amdgcn_mfma_f32_16x16x32_f16(A1, b0, acc1, 0, 0, 0);
  acc2 = __builtin_amdgcn_mfma_f32_16x16x32_f16(A2, b0, acc2, 0, 0, 0);
  acc3 = __builtin_amdgcn_mfma_f32_16x16x32_f16(A3, b0, acc3, 0, 0, 0);
  acc0 = __builtin_amdgcn_mfma_f32_16x16x32_f16(A4, b1, acc0, 0, 0, 0);
  acc1 = __builtin_amdgcn_mfma_f32_16x16x32_f16(A5, b1, acc1, 0, 0, 0);
  acc2 = __builtin_amdgcn_mfma_f32_16x16x32_f16(A6, b1, acc2, 0, 0, 0);
  acc3 = __builtin_amdgcn_mfma_f32_16x16x32_f16(A7, b1, acc3, 0, 0, 0);

  // ---- Epilogue: cross-wave reduce (only barriers in the kernel) ----
  const int mb = quad * 4;
#pragma unroll
  for (int i = 0; i < 4; ++i) red[wave * 1024 + (mb + i)      * 16 + ln] = acc0[i];
#pragma unroll
  for (int i = 0; i < 4; ++i) red[wave * 1024 + (16 + mb + i) * 16 + ln] = acc1[i];
#pragma unroll
  for (int i = 0; i < 4; ++i) red[wave * 1024 + (32 + mb + i) * 16 + ln] = acc2[i];
#pragma unroll
  for (int i = 0; i < 4; ++i) red[wave * 1024 + (48 + mb + i) * 16 + ln] = acc3[i];
  __syncthreads();

  // ---- Plain partial store ----
  float* pp = &part[(size_t)kq * OUTN];
#pragma unroll
  for (int c2 = 0; c2 < 4; ++c2) {
    const int cell = tid + c2 * 256;  // 1024 cells = 64 m x 16 n
    const int mm = cell >> 4, nn = cell & 15;
    pp[mm * OUTF + n0 + nn] =
        red[cell] + red[1024 + cell] + red[2048 + cell] + red[3072 + cell];
  }
}

// ---------------------------------------------------------------------------
// Reduce: out = sum_kq part[kq] + bias. 45 MB read + 2.8 MB write ~ 8 us.
// ---------------------------------------------------------------------------
__global__ __launch_bounds__(256) void reduce_kernel(
    const float* __restrict__ part, const float* __restrict__ bias,
    float* __restrict__ out) {
  const int t  = blockIdx.x * 256 + threadIdx.x;  // 688*256 = 176128 exact
  const int i4 = t * 4;
  floatx4 a = *(const floatx4*)&part[i4];
#pragma unroll
  for (int k = 1; k < KSPL; ++k) {
    const floatx4 b = *(const floatx4*)&part[(size_t)k * OUTN + i4];
    a[0] += b[0]; a[1] += b[1]; a[2] += b[2]; a[3] += b[3];
  }
  const int nn = i4 % OUTF;  // OUTF % 4 == 0: float4 never straddles rows
  const floatx4 bb = *(const floatx4*)&bias[nn];
  a[0] += bb[0]; a[1] += bb[1]; a[2] += bb[2]; a[3] += bb[3];
  *(floatx4*)&out[i4] = a;
}

// ---------------------------------------------------------------------------
// Inputs: 0 x(fp32) 1 int8_data(i32) 2 fp16_data(fp32) 3 scales(fp32)
// 4 bias(fp32) 5 int8_pos(UNUSED) 6 fp16_pos(i32) 7 block_idx(UNUSED)
// ws: x16 (512 KB) | meta (11.3 MB) | part (45.1 MB)
// ---------------------------------------------------------------------------
extern "C" void kernel_launch(void* const* d_in, const int* in_sizes, int n_in,
                              void* d_out, int out_size, void* d_ws,
                              size_t ws_size, hipStream_t stream) {
  const float* x      = (const float*)d_in[0];
  const int*   i8     = (const int*)d_in[1];
  const float* fpdat  = (const float*)d_in[2];
  const float* scales = (const float*)d_in[3];
  const float* bias   = (const float*)d_in[4];
  const int*   fppos  = (const int*)d_in[6];

  char* wsp = (char*)d_ws;
  _Float16* x16  = (_Float16*)wsp;
  int*      meta = (int*)(wsp + (size_t)TOK * INF * sizeof(_Float16));
  float*    part = (float*)(wsp + (size_t)TOK * INF * sizeof(_Float16)
                                + (size_t)NSLC * 16);
  float*    out  = (float*)d_out;

  const int n8 = in_sizes[1];
  const int nf = in_sizes[2];

  precompute_kernel<<<NSLC / 256, 256, 0, stream>>>(x, fppos, nf, x16, meta);
  gemm_fused<<<NBLK * KSPL, 256, 0, stream>>>(x16, i8, fpdat, scales, meta,
                                              part, n8, nf);
  reduce_kernel<<<OUTN / (4 * 256), 256, 0, stream>>>(part, bias, out);
}